// Round 22
// baseline (159.162 us; speedup 1.0000x reference)
//
#include <hip/hip_runtime.h>
#include <math.h>

#define Bb 16
#define Tt 64
#define Nn 64
#define Ss 4
#define Dd 128
#define Hh 8
#define HD 16
#define BN 1024
#define G3 384   // 3*D

// workspace layout (in floats)
#define OFF_WX   0                              // 4*384
#define OFF_BX   1536                           // 384
#define OFF_YS   4096                           // f16 ys: T*BN*D halves (uses half region)
#define OFF_KH   (OFF_YS + Tt*BN*Dd)            // f16 [b,h][t][n][16]
#define OFF_QH   (OFF_KH + Bb*Hh*Tt*Nn*HD/2)
#define OFF_VW1  (OFF_QH + Bb*Hh*Tt*Nn*HD/2)    // f32 [b,h][t][n]
#define OFF_VW2  (OFF_VW1 + Bb*Hh*Tt*Nn)
#define OFF_E    (OFF_VW2 + Bb*Hh*Tt*Nn)        // B*N*N
#define OFF_VV   (OFF_E + Bb*Nn*Nn)             // BN*D
#define OFF_WKQ  (OFF_VV + BN*Dd)               // f16 frag [W_kc|W_qc|u]: 17408 floats
#define OFF_WT   (OFF_WKQ + 17408)              // f16 frag W_hh: 24576 floats
#define OFF_WDF  (OFF_WT + 24576)               // f16 frag W_dec: 16384 floats
#define OFF_WMF  (OFF_WDF + 16384)              // f16 frag [W_mu|W_sig]: 1024 floats
#define WS_FLOATS (OFF_WMF + 1024)

typedef _Float16 half2_t __attribute__((ext_vector_type(2)));
typedef _Float16 f16x8 __attribute__((ext_vector_type(8)));
typedef float f32x4 __attribute__((ext_vector_type(4)));

__device__ __forceinline__ float fast_sigmoid(float v) {
  return 1.f / (1.f + __expf(-v));
}
__device__ __forceinline__ float fast_tanh(float v) {
  float e2 = __expf(2.f * v);
  return 1.f - 2.f / (e2 + 1.f);
}
__device__ __forceinline__ float sel4(f32x4 v, int k) {
  float r = v[0];
  r = (k == 1) ? v[1] : r;
  r = (k == 2) ? v[2] : r;
  r = (k == 3) ? v[3] : r;
  return r;
}
// barrier that drains LDS only (global stores may stay in flight)
__device__ __forceinline__ void lds_barrier() {
  asm volatile("s_waitcnt lgkmcnt(0)" ::: "memory");
  __builtin_amdgcn_sched_barrier(0);
  __builtin_amdgcn_s_barrier();
}

// ---------------- kernel 0: fold weights + pack all MFMA B-fragments + zero E ----------------
// blocks: 0 fold | 1..24 W_hh | 25..41 W_kq+u | 42..49 W_dec | 50 W_mu|W_sig | 51 zero E
__global__ __launch_bounds__(384) void k_precompute(
    const float* __restrict__ W_se, const float* __restrict__ b_se,
    const float* __restrict__ W_ih, const float* __restrict__ b_ih,
    const float* __restrict__ W_hh,
    const float* __restrict__ W_kc, const float* __restrict__ W_qc,
    const float* __restrict__ W_vc, const float* __restrict__ W_att,
    const float* __restrict__ W_dec, const float* __restrict__ W_mu,
    const float* __restrict__ W_sig,
    float* __restrict__ ws) {
  const int tid = threadIdx.x;
  if (blockIdx.x == 51) {
    float4* ez = (float4*)(ws + OFF_E);
    for (int idx = tid; idx < (Bb*Nn*Nn)/4; idx += 384) {
      float4 z = {0.f, 0.f, 0.f, 0.f};
      ez[idx] = z;
    }
    return;
  }
  if (blockIdx.x == 50) {
    _Float16* WF = (_Float16*)(ws + OFF_WMF);
    for (int idx = tid; idx < 4*64*8; idx += 384) {
      int ks = idx >> 9, l = (idx >> 3) & 63, j = idx & 7;
      int k = ks*32 + (l >> 4)*8 + j;
      int c16 = l & 15;
      float v = (c16 < 4) ? W_mu[(size_t)k*Ss + c16]
              : ((c16 < 8) ? W_sig[(size_t)k*Ss + c16 - 4] : 0.f);
      WF[(size_t)(ks*64 + l)*8 + j] = (_Float16)v;
    }
    return;
  }
  if (blockIdx.x >= 42) {
    const int nt = blockIdx.x - 42;  // 0..7
    _Float16* WF = (_Float16*)(ws + OFF_WDF);
    for (int idx = tid; idx < 8*64*8; idx += 384) {
      int ks = idx >> 9, l = (idx >> 3) & 63, j = idx & 7;
      int k = ks*32 + (l >> 4)*8 + j;
      int c = nt*16 + (l & 15);
      WF[(size_t)((nt*8 + ks)*64 + l)*8 + j] = (_Float16)W_dec[(size_t)k*Dd + c];
    }
    return;
  }
  if (blockIdx.x >= 25) {
    const int nt = blockIdx.x - 25;  // 0..16
    _Float16* WF = (_Float16*)(ws + OFF_WKQ);
    for (int idx = tid; idx < 4*64*8; idx += 384) {
      int ks = idx >> 9, l = (idx >> 3) & 63, j = idx & 7;
      int k = ks*32 + (l >> 4)*8 + j;
      int c16 = l & 15;
      float v;
      if (nt < 16) {
        int cg = nt*16 + c16;
        v = (cg < Dd) ? W_kc[(size_t)k*Dd + cg] : W_qc[(size_t)k*Dd + cg - Dd];
      } else {
        int h = c16 >> 1, which = c16 & 1;
        float s = 0.f;
        for (int d = 0; d < HD; ++d)
          s = fmaf(W_vc[(size_t)k*Dd + h*HD + d], W_att[which*Dd + h*HD + d], s);
        v = s;
      }
      WF[(size_t)((nt*4 + ks)*64 + l)*8 + j] = (_Float16)v;
    }
    return;
  }
  if (blockIdx.x > 0) {
    const int nt = blockIdx.x - 1;  // 0..23
    _Float16* WF = (_Float16*)(ws + OFF_WT);
    for (int idx = tid; idx < 4*64*8; idx += 384) {
      int ks = idx >> 9, l = (idx >> 3) & 63, j = idx & 7;
      int k = ks*32 + (l >> 4)*8 + j;
      int c = nt*16 + (l & 15);
      WF[(size_t)((nt*4 + ks)*64 + l)*8 + j] = (_Float16)W_hh[(size_t)k*G3 + c];
    }
    return;
  }
  const int c = tid;
  float* Wx = ws + OFF_WX; float* bx = ws + OFF_BX;
  float accb = b_ih[c];
  float a0 = 0.f, a1 = 0.f, a2 = 0.f, a3 = 0.f;
  for (int k = 0; k < Dd; ++k) {
    float w = W_ih[k*G3 + c];
    accb = fmaf(b_se[k], w, accb);
    a0 = fmaf(W_se[0*Dd + k], w, a0);
    a1 = fmaf(W_se[1*Dd + k], w, a1);
    a2 = fmaf(W_se[2*Dd + k], w, a2);
    a3 = fmaf(W_se[3*Dd + k], w, a3);
  }
  bx[c] = accb;
  Wx[0*G3 + c] = a0; Wx[1*G3 + c] = a1; Wx[2*G3 + c] = a2; Wx[3*G3 + c] = a3;
}

// ---------------- kernel 1: GRU via MFMA — 8 waves (2/SIMD), 16-wide d-range ----------------
__global__ __launch_bounds__(512) void k_gru(
    const float* __restrict__ x, const float* __restrict__ W_init,
    const float* __restrict__ b_init,
    const float* __restrict__ b_hh, float* __restrict__ ws) {
  __shared__ __align__(16) _Float16 h_l[2][4][160];   // 2.5 KB
  __shared__ float xt_l[Tt+1][4][Ss];                 // 4.2 KB
  const int tid = threadIdx.x;
  const int wave = tid >> 6;      // 0..7
  const int lane = tid & 63;
  const int l15 = lane & 15, lk = lane >> 4;
  const int blk = blockIdx.x;     // 0..255
  const int row0 = blk * 4;
  const int b = row0 >> 6, n0 = row0 & 63;
  _Float16* ys = (_Float16*)(ws + OFF_YS);
  const float* Wx = ws + OFF_WX;
  const float* bxp = ws + OFF_BX;

  const f16x8* WF = (const f16x8*)(ws + OFF_WT);
  f16x8 wf[3][4];
  float br[3], bx3[3], wxr[3][4];
  #pragma unroll
  for (int g = 0; g < 3; ++g) {
    const int nt = g*8 + wave;
    #pragma unroll
    for (int ks = 0; ks < 4; ++ks)
      wf[g][ks] = WF[(size_t)((nt*4 + ks)*64) + lane];
    const int c = g*Dd + wave*16 + l15;
    br[g] = b_hh[c];
    bx3[g] = bxp[c];
    #pragma unroll
    for (int s = 0; s < 4; ++s) wxr[g][s] = Wx[s*G3 + c];
  }

  for (int idx = tid; idx < (Tt+1)*4*Ss; idx += 512) {
    int t = idx >> 4, r = (idx >> 2) & 3, s = idx & 3;
    xt_l[t][r][s] = x[((size_t)(b*(Tt+1) + t)*Nn + (n0 + r))*Ss + s];
  }
  __syncthreads();

  const int d = wave*16 + l15;
  float hprev;
  {
    float h0 = b_init[d];
    #pragma unroll
    for (int s = 0; s < Ss; ++s)
      h0 = fmaf(xt_l[0][lk][s], W_init[s*Dd + d], h0);
    hprev = h0;
    h_l[0][lk][d] = (_Float16)h0;
  }
  __syncthreads();

  const size_t ysbase = (size_t)(row0 + lk)*Dd + d;
  for (int t = 0; t < Tt; ++t) {
    const int cur = t & 1, nxt = cur ^ 1;
    f16x8 af[4];
    #pragma unroll
    for (int ks = 0; ks < 4; ++ks)
      af[ks] = *(const f16x8*)&h_l[cur][l15 & 3][ks*32 + lk*8];
    f32x4 a0 = {br[0],br[0],br[0],br[0]};
    f32x4 a1 = {br[1],br[1],br[1],br[1]};
    f32x4 a2 = {br[2],br[2],br[2],br[2]};
    #pragma unroll
    for (int ks = 0; ks < 4; ++ks) {
      a0 = __builtin_amdgcn_mfma_f32_16x16x32_f16(af[ks], wf[0][ks], a0, 0, 0, 0);
      a1 = __builtin_amdgcn_mfma_f32_16x16x32_f16(af[ks], wf[1][ks], a1, 0, 0, 0);
      a2 = __builtin_amdgcn_mfma_f32_16x16x32_f16(af[ks], wf[2][ks], a2, 0, 0, 0);
    }
    const float x0 = xt_l[t][lk][0], x1 = xt_l[t][lk][1];
    const float x2 = xt_l[t][lk][2], x3 = xt_l[t][lk][3];
    {
      float ar = sel4(a0, lk);
      float az = sel4(a1, lk);
      float an = sel4(a2, lk);
      float gi_r = bx3[0], gi_z = bx3[1], gi_n = bx3[2];
      gi_r = fmaf(x0, wxr[0][0], gi_r); gi_r = fmaf(x1, wxr[0][1], gi_r);
      gi_r = fmaf(x2, wxr[0][2], gi_r); gi_r = fmaf(x3, wxr[0][3], gi_r);
      gi_z = fmaf(x0, wxr[1][0], gi_z); gi_z = fmaf(x1, wxr[1][1], gi_z);
      gi_z = fmaf(x2, wxr[1][2], gi_z); gi_z = fmaf(x3, wxr[1][3], gi_z);
      gi_n = fmaf(x0, wxr[2][0], gi_n); gi_n = fmaf(x1, wxr[2][1], gi_n);
      gi_n = fmaf(x2, wxr[2][2], gi_n); gi_n = fmaf(x3, wxr[2][3], gi_n);
      float rg = fast_sigmoid(gi_r + ar);
      float zg = fast_sigmoid(gi_z + az);
      float ng = fast_tanh(fmaf(rg, an, gi_n));
      float hn = fmaf(zg, hprev - ng, ng);
      hprev = hn;
      h_l[nxt][lk][d] = (_Float16)hn;
      ys[(size_t)t*BN*Dd + ysbase] = (_Float16)hn;
    }
    lds_barrier();   // drains LDS only; ys stores stay in flight
  }
}

// ---------------- kernel 2: FUSED k,q,vw (blocks <1024) + decode GRU step/vv (blocks >=1024) ----------------
// Both paths depend only on ys; outputs disjoint (KH/QH/VW vs VV). Decode rides
// concurrently inside the kqv window instead of a serial 13us launch.
__global__ __launch_bounds__(256, 2) void k_kqv_dec(
    const float* __restrict__ x, const float* __restrict__ W_hh,
    const float* __restrict__ b_hh, const float* __restrict__ W_val,
    const float* __restrict__ b_val, float* __restrict__ ws) {
  __shared__ __align__(16) char smem[64*136*2];   // 17408 B, aliased per path
  const int tid = threadIdx.x;

  if (blockIdx.x >= 1024) {
    // ---------- decode path (256 threads) ----------
    float (*h_lds)[Dd] = (float(*)[Dd])smem;                    // 2048 B
    float (*g_lds)[4*Dd] = (float(*)[4*Dd])(smem + 2048);       // 8192 B
    float (*xt)[Ss] = (float(*)[Ss])(smem + 10240);             // 64 B
    const int dblk = blockIdx.x - 1024;   // 0..255
    const int row0 = dblk * 4;
    const int b = row0 >> 6, n0 = row0 & 63;
    const _Float16* ysf = (const _Float16*)(ws + OFF_YS);
    const float* Wx = ws + OFF_WX;
    const float* bxp = ws + OFF_BX;
    if (tid < Dd) {
      for (int r = 0; r < 4; ++r)
        h_lds[r][tid] = (float)ysf[(size_t)((Tt-1)*BN + row0 + r)*Dd + tid];
    }
    if (tid >= 128 && tid < 144) {
      int q = tid - 128; int r = q >> 2, s = q & 3;
      xt[r][s] = x[((size_t)(b*(Tt+1) + Tt)*Nn + (n0 + r))*Ss + s];
    }
    __syncthreads();
    for (int c = tid; c < G3; c += 256) {
      const float bhh = b_hh[c];
      float acc[4] = {bhh, bhh, bhh, bhh};
      for (int k = 0; k < Dd; k += 4) {
        float w0 = W_hh[(k+0)*G3 + c];
        float w1 = W_hh[(k+1)*G3 + c];
        float w2 = W_hh[(k+2)*G3 + c];
        float w3 = W_hh[(k+3)*G3 + c];
        #pragma unroll
        for (int r = 0; r < 4; ++r) {
          float4 hv = *(const float4*)&h_lds[r][k];
          acc[r] = fmaf(hv.x, w0, acc[r]);
          acc[r] = fmaf(hv.y, w1, acc[r]);
          acc[r] = fmaf(hv.z, w2, acc[r]);
          acc[r] = fmaf(hv.w, w3, acc[r]);
        }
      }
      const float bxv = bxp[c];
      const float wx0 = Wx[0*G3 + c], wx1 = Wx[1*G3 + c];
      const float wx2 = Wx[2*G3 + c], wx3 = Wx[3*G3 + c];
      float gi[4];
      #pragma unroll
      for (int r = 0; r < 4; ++r) {
        float g = bxv;
        g = fmaf(xt[r][0], wx0, g);
        g = fmaf(xt[r][1], wx1, g);
        g = fmaf(xt[r][2], wx2, g);
        g = fmaf(xt[r][3], wx3, g);
        gi[r] = g;
      }
      if (c < 2*Dd) {
        #pragma unroll
        for (int r = 0; r < 4; ++r) g_lds[r][c] = acc[r] + gi[r];
      } else {
        #pragma unroll
        for (int r = 0; r < 4; ++r) { g_lds[r][c] = gi[r]; g_lds[r][c + Dd] = acc[r]; }
      }
    }
    __syncthreads();
    if (tid < Dd) {
      const int d = tid;
      #pragma unroll
      for (int r = 0; r < 4; ++r) {
        float rg = fast_sigmoid(g_lds[r][d]);
        float zg = fast_sigmoid(g_lds[r][Dd + d]);
        float ng = fast_tanh(fmaf(rg, g_lds[r][3*Dd + d], g_lds[r][2*Dd + d]));
        float hn = fmaf(zg, h_lds[r][d] - ng, ng);
        h_lds[r][d] = hn;
      }
    }
    __syncthreads();
    if (tid < Dd) {
      const int c2 = tid;
      for (int r = 0; r < 4; ++r) {
        float a = b_val[c2];
        for (int k = 0; k < Dd; k += 4) {
          float4 hv = *(const float4*)&h_lds[r][k];
          a = fmaf(hv.x, W_val[(k+0)*Dd + c2], a);
          a = fmaf(hv.y, W_val[(k+1)*Dd + c2], a);
          a = fmaf(hv.z, W_val[(k+2)*Dd + c2], a);
          a = fmaf(hv.w, W_val[(k+3)*Dd + c2], a);
        }
        ws[OFF_VV + (size_t)(row0 + r)*Dd + c2] = a;
      }
    }
    return;
  }

  // ---------- kqv path (256 threads) ----------
  _Float16 (*ysl)[136] = (_Float16(*)[136])smem;
  const int blk = blockIdx.x;    // b*T + t
  const int b = blk >> 6, t = blk & 63;
  const int wave = tid >> 6, lane = tid & 63;
  const int l15 = lane & 15, lk = lane >> 4;

  const f16x8* WKQ = (const f16x8*)(ws + OFF_WKQ);
  f16x8 bf0[4], bf1[4], bf2[4], bf3[4], bu[4];
  #pragma unroll
  for (int ks = 0; ks < 4; ++ks) {
    bf0[ks] = WKQ[(size_t)((wave*4 + 0)*4 + ks)*64 + lane];
    bf1[ks] = WKQ[(size_t)((wave*4 + 1)*4 + ks)*64 + lane];
    bf2[ks] = WKQ[(size_t)((wave*4 + 2)*4 + ks)*64 + lane];
    bf3[ks] = WKQ[(size_t)((wave*4 + 3)*4 + ks)*64 + lane];
    bu[ks]  = WKQ[(size_t)(16*4 + ks)*64 + lane];
  }

  const _Float16* ysrc = (const _Float16*)(ws + OFF_YS) + ((size_t)t*BN + b*64)*Dd;
  for (int idx = tid; idx < 64*8; idx += 256) {
    int r = idx >> 3, k16 = (idx & 7)*16;
    *(f16x8*)&ysl[r][k16]     = *(const f16x8*)&ysrc[r*Dd + k16];
    *(f16x8*)&ysl[r][k16 + 8] = *(const f16x8*)&ysrc[r*Dd + k16 + 8];
  }
  __syncthreads();

  _Float16* khd = (_Float16*)(ws + OFF_KH);
  _Float16* qhd = (_Float16*)(ws + OFF_QH);

  #pragma unroll
  for (int mt = 0; mt < 4; ++mt) {
    f16x8 af[4];
    #pragma unroll
    for (int ks = 0; ks < 4; ++ks)
      af[ks] = *(const f16x8*)&ysl[mt*16 + l15][ks*32 + lk*8];
    f32x4 a0 = {0.f,0.f,0.f,0.f}, a1 = a0, a2 = a0, a3 = a0;
    #pragma unroll
    for (int ks = 0; ks < 4; ++ks) {
      a0 = __builtin_amdgcn_mfma_f32_16x16x32_f16(af[ks], bf0[ks], a0, 0, 0, 0);
      a1 = __builtin_amdgcn_mfma_f32_16x16x32_f16(af[ks], bf1[ks], a1, 0, 0, 0);
      a2 = __builtin_amdgcn_mfma_f32_16x16x32_f16(af[ks], bf2[ks], a2, 0, 0, 0);
      a3 = __builtin_amdgcn_mfma_f32_16x16x32_f16(af[ks], bf3[ks], a3, 0, 0, 0);
    }
    const int rowb = mt*16 + lk*4;
    #pragma unroll
    for (int nti = 0; nti < 4; ++nti) {
      f32x4 av = (nti == 0) ? a0 : (nti == 1) ? a1 : (nti == 2) ? a2 : a3;
      const int gc = wave*64 + nti*16 + l15;
      const int hh = (gc >> 4) & 7;
      const int dd2 = gc & 15;
      _Float16* base = (gc < Dd) ? khd : qhd;
      const size_t rowbase = ((size_t)(b*Hh + hh)*Tt + t)*Nn*HD;
      #pragma unroll
      for (int rg2 = 0; rg2 < 4; ++rg2)
        base[rowbase + (size_t)(rowb + rg2)*HD + dd2] = (_Float16)av[rg2];
    }
    if (wave == 3) {
      f32x4 au = {0.f,0.f,0.f,0.f};
      #pragma unroll
      for (int ks = 0; ks < 4; ++ks)
        au = __builtin_amdgcn_mfma_f32_16x16x32_f16(af[ks], bu[ks], au, 0, 0, 0);
      const int h = l15 >> 1, which = l15 & 1;
      float* vw = ws + (which ? OFF_VW2 : OFF_VW1) + ((size_t)(b*Hh + h)*Tt + t)*Nn;
      #pragma unroll
      for (int rg2 = 0; rg2 < 4; ++rg2)
        vw[rowb + rg2] = au[rg2];
    }
  }
}

// ---------------- kernel 3: attn — QK^T via MFMA (zero-padded K=16), clamp-exp ----------------
__global__ __launch_bounds__(1024) void k_attn(float* __restrict__ ws) {
  __shared__ float vw1_l[Tt][Nn];   // 16 KB
  __shared__ float vw2_l[Tt][Nn];   // 16 KB
  const int tid = threadIdx.x;
  const int bh = blockIdx.x;
  const int b = bh >> 3;
  const int wave = tid >> 6;
  const int it = wave >> 2, jt = wave & 3;
  const int i0 = it*16, j0 = jt*16;
  const int lane = tid & 63;
  const int l15 = lane & 15, lk = lane >> 4;
  const _Float16* kh = (const _Float16*)(ws + OFF_KH) + (size_t)bh*Tt*Nn*HD;
  const _Float16* qh = (const _Float16*)(ws + OFF_QH) + (size_t)bh*Tt*Nn*HD;
  const float* vw1 = ws + OFF_VW1 + (size_t)bh*Tt*Nn;
  const float* vw2 = ws + OFF_VW2 + (size_t)bh*Tt*Nn;
  float* e = ws + OFF_E + (size_t)b*Nn*Nn;
  const float scale = 0.08838834764831845f; // 1/sqrt(128)

  #pragma unroll
  for (int s = 0; s < 4; ++s) {
    int idx = tid + s*1024;
    ((float*)vw1_l)[idx] = vw1[idx];
    ((float*)vw2_l)[idx] = vw2[idx];
  }
  __syncthreads();

  float S[4] = {0.f,0.f,0.f,0.f};
  float A1[4] = {0.f,0.f,0.f,0.f};
  float A2[4] = {0.f,0.f,0.f,0.f};
  const bool realk = (lk < 2);   // lanes lk>=2 feed zeros (K padded 16->32)

  #pragma unroll 4
  for (int t = 0; t < Tt; ++t) {
    f16x8 af = {0,0,0,0,0,0,0,0}, bf = {0,0,0,0,0,0,0,0};
    if (realk) {
      af = *(const f16x8*)&kh[((size_t)t*Nn + i0 + l15)*HD + lk*8];
      bf = *(const f16x8*)&qh[((size_t)t*Nn + j0 + l15)*HD + lk*8];
    }
    f32x4 sc = {0.f,0.f,0.f,0.f};
    sc = __builtin_amdgcn_mfma_f32_16x16x32_f16(af, bf, sc, 0, 0, 0);
    float4 w1 = *(const float4*)&vw1_l[t][i0 + lk*4];
    float4 w2 = *(const float4*)&vw2_l[t][i0 + lk*4];
    const float* w1p = (const float*)&w1;
    const float* w2p = (const float*)&w2;
    #pragma unroll
    for (int r = 0; r < 4; ++r) {
      float s = fminf(fmaxf(sc[r] * scale, -60.f), 60.f);
      float ee = __expf(s);
      S[r] += ee;
      A1[r] = fmaf(ee, w1p[r], A1[r]);
      A2[r] = fmaf(ee, w2p[r], A2[r]);
    }
  }
  {
    const int j = j0 + l15;
    #pragma unroll
    for (int r = 0; r < 4; ++r) {
      const int i = i0 + lk*4 + r;
      float inv = 1.f / S[r];
      atomicAdd(&e[i*Nn + j], A1[r] * inv);
      atomicAdd(&e[j*Nn + i], A2[r] * inv);
    }
  }
}

// ---------------- kernel 5: weight/p/dec/mu/sig — all via MFMA ----------------
__global__ __launch_bounds__(256) void k_final(
    const float* __restrict__ b_dec, const float* __restrict__ b_mu,
    const float* __restrict__ b_sig, const float* __restrict__ b_att,
    float* __restrict__ ws, float* __restrict__ out) {
  __shared__ __align__(16) _Float16 vvT[Dd][72];
  __shared__ __align__(16) _Float16 wl[16][72];
  __shared__ __align__(16) _Float16 A2[16][264];
  __shared__ __align__(16) _Float16 A3[16][136];
  const int tid = threadIdx.x;
  const int wave = tid >> 6, lane = tid & 63;
  const int l15 = lane & 15, lk = lane >> 4;
  const int blk = blockIdx.x;
  const int b = blk >> 2, iq = blk & 3, i0 = iq*16;
  const float* vv = ws + OFF_VV + (size_t)b*64*Dd;
  const float* e  = ws + OFF_E + (size_t)b*Nn*Nn;
  const float batt = b_att[0];

  for (int idx = tid; idx < 64*Dd/4; idx += 256) {
    int r = idx >> 5, k4 = (idx & 31)*4;
    float4 v = *(const float4*)&vv[r*Dd + k4];
    vvT[k4+0][r] = (_Float16)v.x;
    vvT[k4+1][r] = (_Float16)v.y;
    vvT[k4+2][r] = (_Float16)v.z;
    vvT[k4+3][r] = (_Float16)v.w;
    int rl = r - i0;
    if (rl >= 0 && rl < 16) {
      A2[rl][k4+0] = (_Float16)v.x;
      A2[rl][k4+1] = (_Float16)v.y;
      A2[rl][k4+2] = (_Float16)v.z;
      A2[rl][k4+3] = (_Float16)v.w;
    }
  }
  for (int idx = tid; idx < 16*64; idx += 256) {
    int il = idx >> 6, jj = idx & 63;
    int i = i0 + il;
    float v = (i == jj) ? 0.f : fast_tanh(e[i*Nn + jj] + batt + 0.5f);
    wl[il][jj] = (_Float16)v;
  }
  __syncthreads();

  {
    f16x8 a0 = *(const f16x8*)&wl[l15][lk*8];
    f16x8 a1 = *(const f16x8*)&wl[l15][32 + lk*8];
    #pragma unroll
    for (int q = 0; q < 2; ++q) {
      const int nt = wave*2 + q;
      f16x8 b0 = *(const f16x8*)&vvT[nt*16 + l15][lk*8];
      f16x8 b1 = *(const f16x8*)&vvT[nt*16 + l15][32 + lk*8];
      f32x4 acc = {0.f,0.f,0.f,0.f};
      acc = __builtin_amdgcn_mfma_f32_16x16x32_f16(a0, b0, acc, 0, 0, 0);
      acc = __builtin_amdgcn_mfma_f32_16x16x32_f16(a1, b1, acc, 0, 0, 0);
      #pragma unroll
      for (int r = 0; r < 4; ++r)
        A2[lk*4 + r][128 + nt*16 + l15] = (_Float16)(acc[r] * (1.f/64.f));
    }
  }
  __syncthreads();

  const f16x8* WDF = (const f16x8*)(ws + OFF_WDF);
  {
    f16x8 ad[8];
    #pragma unroll
    for (int ks = 0; ks < 8; ++ks)
      ad[ks] = *(const f16x8*)&A2[l15][ks*32 + lk*8];
    #pragma unroll
    for (int q = 0; q < 2; ++q) {
      const int nt = wave*2 + q;
      const float bias = b_dec[nt*16 + l15];
      f32x4 acc = {bias, bias, bias, bias};
      #pragma unroll
      for (int ks = 0; ks < 8; ++ks)
        acc = __builtin_amdgcn_mfma_f32_16x16x32_f16(
            ad[ks], WDF[(size_t)((nt*8 + ks)*64) + lane], acc, 0, 0, 0);
      #pragma unroll
      for (int r = 0; r < 4; ++r)
        A3[lk*4 + r][nt*16 + l15] = (_Float16)acc[r];
    }
  }
  __syncthreads();

  if (wave == 0) {
    const f16x8* WMF = (const f16x8*)(ws + OFF_WMF);
    f16x8 ah[4];
    #pragma unroll
    for (int ks = 0; ks < 4; ++ks)
      ah[ks] = *(const f16x8*)&A3[l15][ks*32 + lk*8];
    const float bias = (l15 < 4) ? b_mu[l15] : ((l15 < 8) ? b_sig[l15 - 4] : 0.f);
    f32x4 acc = {bias, bias, bias, bias};
    #pragma unroll
    for (int ks = 0; ks < 4; ++ks)
      acc = __builtin_amdgcn_mfma_f32_16x16x32_f16(
          ah[ks], WMF[(size_t)(ks*64) + lane], acc, 0, 0, 0);
    if (l15 < 8) {
      const int which = l15 >> 2, s = l15 & 3;
      #pragma unroll
      for (int r = 0; r < 4; ++r) {
        float v = acc[r];
        if (which) v = 1.f/(1.f + __expf(-v)) + 1e-6f;
        out[(size_t)which*(Bb*Nn*Ss) + (size_t)(b*64 + i0 + lk*4 + r)*Ss + s] = v;
      }
    }
  }
}

extern "C" void kernel_launch(void* const* d_in, const int* in_sizes, int n_in,
                              void* d_out, int out_size, void* d_ws, size_t ws_size,
                              hipStream_t stream) {
  const float* x     = (const float*)d_in[0];
  const float* W_se  = (const float*)d_in[1];
  const float* b_se  = (const float*)d_in[2];
  const float* W_init= (const float*)d_in[3];
  const float* b_init= (const float*)d_in[4];
  const float* W_ih  = (const float*)d_in[5];
  const float* W_hh  = (const float*)d_in[6];
  const float* b_ih  = (const float*)d_in[7];
  const float* b_hh  = (const float*)d_in[8];
  const float* W_kc  = (const float*)d_in[9];
  const float* W_qc  = (const float*)d_in[10];
  const float* W_vc  = (const float*)d_in[11];
  const float* W_att = (const float*)d_in[12];
  const float* b_att = (const float*)d_in[13];
  const float* W_val = (const float*)d_in[14];
  const float* b_val = (const float*)d_in[15];
  const float* W_dec = (const float*)d_in[16];
  const float* b_dec = (const float*)d_in[17];
  const float* W_mu  = (const float*)d_in[18];
  const float* b_mu  = (const float*)d_in[19];
  const float* W_sig = (const float*)d_in[20];
  const float* b_sig = (const float*)d_in[21];
  float* ws = (float*)d_ws;
  float* out = (float*)d_out;

  if (ws_size < (size_t)WS_FLOATS * sizeof(float)) return;

  k_precompute<<<52, 384, 0, stream>>>(W_se, b_se, W_ih, b_ih, W_hh, W_kc, W_qc,
                                       W_vc, W_att, W_dec, W_mu, W_sig, ws);
  k_gru<<<BN/4, 512, 0, stream>>>(x, W_init, b_init, b_hh, ws);
  k_kqv_dec<<<Bb*Tt + BN/4, 256, 0, stream>>>(x, W_hh, b_hh, W_val, b_val, ws);
  k_attn<<<Bb*Hh, 1024, 0, stream>>>(ws);
  k_final<<<Bb*4, 256, 0, stream>>>(b_dec, b_mu, b_sig, b_att, ws, out);
}

// Round 23
// 120.425 us; speedup vs baseline: 1.3217x; 1.3217x over previous
//
#include <hip/hip_runtime.h>
#include <math.h>

#define Bb 16
#define Tt 64
#define Nn 64
#define Ss 4
#define Dd 128
#define Hh 8
#define HD 16
#define BN 1024
#define G3 384   // 3*D

// workspace layout (in floats)
#define OFF_WX   0                              // 4*384
#define OFF_BX   1536                           // 384
#define OFF_YS   4096                           // f16 ys: T*BN*D halves (uses half region)
#define OFF_KH   (OFF_YS + Tt*BN*Dd)            // f16 [b,h][t][n][16]
#define OFF_QH   (OFF_KH + Bb*Hh*Tt*Nn*HD/2)
#define OFF_VW1  (OFF_QH + Bb*Hh*Tt*Nn*HD/2)    // f32 [b,h][t][n]
#define OFF_VW2  (OFF_VW1 + Bb*Hh*Tt*Nn)
#define OFF_E    (OFF_VW2 + Bb*Hh*Tt*Nn)        // B*N*N
#define OFF_VV   (OFF_E + Bb*Nn*Nn)             // BN*D
#define OFF_WKQ  (OFF_VV + BN*Dd)               // f16 frag [W_kc|W_qc|u]: 17408 floats
#define OFF_WT   (OFF_WKQ + 17408)              // f16 frag W_hh: 24576 floats
#define OFF_WDF  (OFF_WT + 24576)               // f16 frag W_dec: 16384 floats
#define OFF_WMF  (OFF_WDF + 16384)              // f16 frag [W_mu|W_sig]: 1024 floats
#define WS_FLOATS (OFF_WMF + 1024)

typedef _Float16 half2_t __attribute__((ext_vector_type(2)));
typedef _Float16 f16x8 __attribute__((ext_vector_type(8)));
typedef float f32x4 __attribute__((ext_vector_type(4)));

__device__ __forceinline__ float fast_sigmoid(float v) {
  return 1.f / (1.f + __expf(-v));
}
__device__ __forceinline__ float fast_tanh(float v) {
  float e2 = __expf(2.f * v);
  return 1.f - 2.f / (e2 + 1.f);
}
__device__ __forceinline__ float sel4(f32x4 v, int k) {
  float r = v[0];
  r = (k == 1) ? v[1] : r;
  r = (k == 2) ? v[2] : r;
  r = (k == 3) ? v[3] : r;
  return r;
}
// barrier that drains LDS only (global stores may stay in flight)
__device__ __forceinline__ void lds_barrier() {
  asm volatile("s_waitcnt lgkmcnt(0)" ::: "memory");
  __builtin_amdgcn_sched_barrier(0);
  __builtin_amdgcn_s_barrier();
}

// ---------------- kernel 0: fold weights + pack all MFMA B-fragments + zero E ----------------
// blocks: 0 fold | 1..24 W_hh | 25..41 W_kq+u | 42..49 W_dec | 50 W_mu|W_sig | 51 zero E
__global__ __launch_bounds__(384) void k_precompute(
    const float* __restrict__ W_se, const float* __restrict__ b_se,
    const float* __restrict__ W_ih, const float* __restrict__ b_ih,
    const float* __restrict__ W_hh,
    const float* __restrict__ W_kc, const float* __restrict__ W_qc,
    const float* __restrict__ W_vc, const float* __restrict__ W_att,
    const float* __restrict__ W_dec, const float* __restrict__ W_mu,
    const float* __restrict__ W_sig,
    float* __restrict__ ws) {
  const int tid = threadIdx.x;
  if (blockIdx.x == 51) {
    float4* ez = (float4*)(ws + OFF_E);
    for (int idx = tid; idx < (Bb*Nn*Nn)/4; idx += 384) {
      float4 z = {0.f, 0.f, 0.f, 0.f};
      ez[idx] = z;
    }
    return;
  }
  if (blockIdx.x == 50) {
    _Float16* WF = (_Float16*)(ws + OFF_WMF);
    for (int idx = tid; idx < 4*64*8; idx += 384) {
      int ks = idx >> 9, l = (idx >> 3) & 63, j = idx & 7;
      int k = ks*32 + (l >> 4)*8 + j;
      int c16 = l & 15;
      float v = (c16 < 4) ? W_mu[(size_t)k*Ss + c16]
              : ((c16 < 8) ? W_sig[(size_t)k*Ss + c16 - 4] : 0.f);
      WF[(size_t)(ks*64 + l)*8 + j] = (_Float16)v;
    }
    return;
  }
  if (blockIdx.x >= 42) {
    const int nt = blockIdx.x - 42;  // 0..7
    _Float16* WF = (_Float16*)(ws + OFF_WDF);
    for (int idx = tid; idx < 8*64*8; idx += 384) {
      int ks = idx >> 9, l = (idx >> 3) & 63, j = idx & 7;
      int k = ks*32 + (l >> 4)*8 + j;
      int c = nt*16 + (l & 15);
      WF[(size_t)((nt*8 + ks)*64 + l)*8 + j] = (_Float16)W_dec[(size_t)k*Dd + c];
    }
    return;
  }
  if (blockIdx.x >= 25) {
    const int nt = blockIdx.x - 25;  // 0..16
    _Float16* WF = (_Float16*)(ws + OFF_WKQ);
    for (int idx = tid; idx < 4*64*8; idx += 384) {
      int ks = idx >> 9, l = (idx >> 3) & 63, j = idx & 7;
      int k = ks*32 + (l >> 4)*8 + j;
      int c16 = l & 15;
      float v;
      if (nt < 16) {
        int cg = nt*16 + c16;
        v = (cg < Dd) ? W_kc[(size_t)k*Dd + cg] : W_qc[(size_t)k*Dd + cg - Dd];
      } else {
        int h = c16 >> 1, which = c16 & 1;
        float s = 0.f;
        for (int d = 0; d < HD; ++d)
          s = fmaf(W_vc[(size_t)k*Dd + h*HD + d], W_att[which*Dd + h*HD + d], s);
        v = s;
      }
      WF[(size_t)((nt*4 + ks)*64 + l)*8 + j] = (_Float16)v;
    }
    return;
  }
  if (blockIdx.x > 0) {
    const int nt = blockIdx.x - 1;  // 0..23
    _Float16* WF = (_Float16*)(ws + OFF_WT);
    for (int idx = tid; idx < 4*64*8; idx += 384) {
      int ks = idx >> 9, l = (idx >> 3) & 63, j = idx & 7;
      int k = ks*32 + (l >> 4)*8 + j;
      int c = nt*16 + (l & 15);
      WF[(size_t)((nt*4 + ks)*64 + l)*8 + j] = (_Float16)W_hh[(size_t)k*G3 + c];
    }
    return;
  }
  const int c = tid;
  float* Wx = ws + OFF_WX; float* bx = ws + OFF_BX;
  float accb = b_ih[c];
  float a0 = 0.f, a1 = 0.f, a2 = 0.f, a3 = 0.f;
  for (int k = 0; k < Dd; ++k) {
    float w = W_ih[k*G3 + c];
    accb = fmaf(b_se[k], w, accb);
    a0 = fmaf(W_se[0*Dd + k], w, a0);
    a1 = fmaf(W_se[1*Dd + k], w, a1);
    a2 = fmaf(W_se[2*Dd + k], w, a2);
    a3 = fmaf(W_se[3*Dd + k], w, a3);
  }
  bx[c] = accb;
  Wx[0*G3 + c] = a0; Wx[1*G3 + c] = a1; Wx[2*G3 + c] = a2; Wx[3*G3 + c] = a3;
}

// ---------------- kernel 1: GRU via MFMA — 8 waves (2/SIMD), 16-wide d-range ----------------
__global__ __launch_bounds__(512) void k_gru(
    const float* __restrict__ x, const float* __restrict__ W_init,
    const float* __restrict__ b_init,
    const float* __restrict__ b_hh, float* __restrict__ ws) {
  __shared__ __align__(16) _Float16 h_l[2][4][160];   // 2.5 KB
  __shared__ float xt_l[Tt+1][4][Ss];                 // 4.2 KB
  const int tid = threadIdx.x;
  const int wave = tid >> 6;      // 0..7
  const int lane = tid & 63;
  const int l15 = lane & 15, lk = lane >> 4;
  const int blk = blockIdx.x;     // 0..255
  const int row0 = blk * 4;
  const int b = row0 >> 6, n0 = row0 & 63;
  _Float16* ys = (_Float16*)(ws + OFF_YS);
  const float* Wx = ws + OFF_WX;
  const float* bxp = ws + OFF_BX;

  const f16x8* WF = (const f16x8*)(ws + OFF_WT);
  f16x8 wf[3][4];
  float br[3], bx3[3], wxr[3][4];
  #pragma unroll
  for (int g = 0; g < 3; ++g) {
    const int nt = g*8 + wave;
    #pragma unroll
    for (int ks = 0; ks < 4; ++ks)
      wf[g][ks] = WF[(size_t)((nt*4 + ks)*64) + lane];
    const int c = g*Dd + wave*16 + l15;
    br[g] = b_hh[c];
    bx3[g] = bxp[c];
    #pragma unroll
    for (int s = 0; s < 4; ++s) wxr[g][s] = Wx[s*G3 + c];
  }

  for (int idx = tid; idx < (Tt+1)*4*Ss; idx += 512) {
    int t = idx >> 4, r = (idx >> 2) & 3, s = idx & 3;
    xt_l[t][r][s] = x[((size_t)(b*(Tt+1) + t)*Nn + (n0 + r))*Ss + s];
  }
  __syncthreads();

  const int d = wave*16 + l15;
  float hprev;
  {
    float h0 = b_init[d];
    #pragma unroll
    for (int s = 0; s < Ss; ++s)
      h0 = fmaf(xt_l[0][lk][s], W_init[s*Dd + d], h0);
    hprev = h0;
    h_l[0][lk][d] = (_Float16)h0;
  }
  __syncthreads();

  const size_t ysbase = (size_t)(row0 + lk)*Dd + d;
  for (int t = 0; t < Tt; ++t) {
    const int cur = t & 1, nxt = cur ^ 1;
    f16x8 af[4];
    #pragma unroll
    for (int ks = 0; ks < 4; ++ks)
      af[ks] = *(const f16x8*)&h_l[cur][l15 & 3][ks*32 + lk*8];
    f32x4 a0 = {br[0],br[0],br[0],br[0]};
    f32x4 a1 = {br[1],br[1],br[1],br[1]};
    f32x4 a2 = {br[2],br[2],br[2],br[2]};
    #pragma unroll
    for (int ks = 0; ks < 4; ++ks) {
      a0 = __builtin_amdgcn_mfma_f32_16x16x32_f16(af[ks], wf[0][ks], a0, 0, 0, 0);
      a1 = __builtin_amdgcn_mfma_f32_16x16x32_f16(af[ks], wf[1][ks], a1, 0, 0, 0);
      a2 = __builtin_amdgcn_mfma_f32_16x16x32_f16(af[ks], wf[2][ks], a2, 0, 0, 0);
    }
    const float x0 = xt_l[t][lk][0], x1 = xt_l[t][lk][1];
    const float x2 = xt_l[t][lk][2], x3 = xt_l[t][lk][3];
    {
      float ar = sel4(a0, lk);
      float az = sel4(a1, lk);
      float an = sel4(a2, lk);
      float gi_r = bx3[0], gi_z = bx3[1], gi_n = bx3[2];
      gi_r = fmaf(x0, wxr[0][0], gi_r); gi_r = fmaf(x1, wxr[0][1], gi_r);
      gi_r = fmaf(x2, wxr[0][2], gi_r); gi_r = fmaf(x3, wxr[0][3], gi_r);
      gi_z = fmaf(x0, wxr[1][0], gi_z); gi_z = fmaf(x1, wxr[1][1], gi_z);
      gi_z = fmaf(x2, wxr[1][2], gi_z); gi_z = fmaf(x3, wxr[1][3], gi_z);
      gi_n = fmaf(x0, wxr[2][0], gi_n); gi_n = fmaf(x1, wxr[2][1], gi_n);
      gi_n = fmaf(x2, wxr[2][2], gi_n); gi_n = fmaf(x3, wxr[2][3], gi_n);
      float rg = fast_sigmoid(gi_r + ar);
      float zg = fast_sigmoid(gi_z + az);
      float ng = fast_tanh(fmaf(rg, an, gi_n));
      float hn = fmaf(zg, hprev - ng, ng);
      hprev = hn;
      h_l[nxt][lk][d] = (_Float16)hn;
      ys[(size_t)t*BN*Dd + ysbase] = (_Float16)hn;
    }
    lds_barrier();   // drains LDS only; ys stores stay in flight
  }
}

// ---------------- kernel 2: k,q,vw via MFMA (f16); ys read as f16 ----------------
__global__ __launch_bounds__(256, 2) void k_kqv(float* __restrict__ ws) {
  __shared__ __align__(16) _Float16 ysl[64][136];
  const int tid = threadIdx.x;
  const int blk = blockIdx.x;    // b*T + t
  const int b = blk >> 6, t = blk & 63;
  const int wave = tid >> 6, lane = tid & 63;
  const int l15 = lane & 15, lk = lane >> 4;

  const f16x8* WKQ = (const f16x8*)(ws + OFF_WKQ);
  f16x8 bf0[4], bf1[4], bf2[4], bf3[4], bu[4];
  #pragma unroll
  for (int ks = 0; ks < 4; ++ks) {
    bf0[ks] = WKQ[(size_t)((wave*4 + 0)*4 + ks)*64 + lane];
    bf1[ks] = WKQ[(size_t)((wave*4 + 1)*4 + ks)*64 + lane];
    bf2[ks] = WKQ[(size_t)((wave*4 + 2)*4 + ks)*64 + lane];
    bf3[ks] = WKQ[(size_t)((wave*4 + 3)*4 + ks)*64 + lane];
    bu[ks]  = WKQ[(size_t)(16*4 + ks)*64 + lane];
  }

  const _Float16* ysrc = (const _Float16*)(ws + OFF_YS) + ((size_t)t*BN + b*64)*Dd;
  for (int idx = tid; idx < 64*8; idx += 256) {
    int r = idx >> 3, k16 = (idx & 7)*16;
    *(f16x8*)&ysl[r][k16]     = *(const f16x8*)&ysrc[r*Dd + k16];
    *(f16x8*)&ysl[r][k16 + 8] = *(const f16x8*)&ysrc[r*Dd + k16 + 8];
  }
  __syncthreads();

  _Float16* khd = (_Float16*)(ws + OFF_KH);
  _Float16* qhd = (_Float16*)(ws + OFF_QH);

  #pragma unroll
  for (int mt = 0; mt < 4; ++mt) {
    f16x8 af[4];
    #pragma unroll
    for (int ks = 0; ks < 4; ++ks)
      af[ks] = *(const f16x8*)&ysl[mt*16 + l15][ks*32 + lk*8];
    f32x4 a0 = {0.f,0.f,0.f,0.f}, a1 = a0, a2 = a0, a3 = a0;
    #pragma unroll
    for (int ks = 0; ks < 4; ++ks) {
      a0 = __builtin_amdgcn_mfma_f32_16x16x32_f16(af[ks], bf0[ks], a0, 0, 0, 0);
      a1 = __builtin_amdgcn_mfma_f32_16x16x32_f16(af[ks], bf1[ks], a1, 0, 0, 0);
      a2 = __builtin_amdgcn_mfma_f32_16x16x32_f16(af[ks], bf2[ks], a2, 0, 0, 0);
      a3 = __builtin_amdgcn_mfma_f32_16x16x32_f16(af[ks], bf3[ks], a3, 0, 0, 0);
    }
    const int rowb = mt*16 + lk*4;
    #pragma unroll
    for (int nti = 0; nti < 4; ++nti) {
      f32x4 av = (nti == 0) ? a0 : (nti == 1) ? a1 : (nti == 2) ? a2 : a3;
      const int gc = wave*64 + nti*16 + l15;
      const int hh = (gc >> 4) & 7;
      const int dd2 = gc & 15;
      _Float16* base = (gc < Dd) ? khd : qhd;
      const size_t rowbase = ((size_t)(b*Hh + hh)*Tt + t)*Nn*HD;
      #pragma unroll
      for (int rg2 = 0; rg2 < 4; ++rg2)
        base[rowbase + (size_t)(rowb + rg2)*HD + dd2] = (_Float16)av[rg2];
    }
    if (wave == 3) {
      f32x4 au = {0.f,0.f,0.f,0.f};
      #pragma unroll
      for (int ks = 0; ks < 4; ++ks)
        au = __builtin_amdgcn_mfma_f32_16x16x32_f16(af[ks], bu[ks], au, 0, 0, 0);
      const int h = l15 >> 1, which = l15 & 1;
      float* vw = ws + (which ? OFF_VW2 : OFF_VW1) + ((size_t)(b*Hh + h)*Tt + t)*Nn;
      #pragma unroll
      for (int rg2 = 0; rg2 < 4; ++rg2)
        vw[rowb + rg2] = au[rg2];
    }
  }
}

// ---------------- kernel 3: attn — QK^T via MFMA (zero-padded K=16), clamp-exp ----------------
__global__ __launch_bounds__(1024) void k_attn(float* __restrict__ ws) {
  __shared__ float vw1_l[Tt][Nn];   // 16 KB
  __shared__ float vw2_l[Tt][Nn];   // 16 KB
  const int tid = threadIdx.x;
  const int bh = blockIdx.x;
  const int b = bh >> 3;
  const int wave = tid >> 6;
  const int it = wave >> 2, jt = wave & 3;
  const int i0 = it*16, j0 = jt*16;
  const int lane = tid & 63;
  const int l15 = lane & 15, lk = lane >> 4;
  const _Float16* kh = (const _Float16*)(ws + OFF_KH) + (size_t)bh*Tt*Nn*HD;
  const _Float16* qh = (const _Float16*)(ws + OFF_QH) + (size_t)bh*Tt*Nn*HD;
  const float* vw1 = ws + OFF_VW1 + (size_t)bh*Tt*Nn;
  const float* vw2 = ws + OFF_VW2 + (size_t)bh*Tt*Nn;
  float* e = ws + OFF_E + (size_t)b*Nn*Nn;
  const float scale = 0.08838834764831845f; // 1/sqrt(128)

  #pragma unroll
  for (int s = 0; s < 4; ++s) {
    int idx = tid + s*1024;
    ((float*)vw1_l)[idx] = vw1[idx];
    ((float*)vw2_l)[idx] = vw2[idx];
  }
  __syncthreads();

  float S[4] = {0.f,0.f,0.f,0.f};
  float A1[4] = {0.f,0.f,0.f,0.f};
  float A2[4] = {0.f,0.f,0.f,0.f};
  const bool realk = (lk < 2);   // lanes lk>=2 feed zeros (K padded 16->32)

  #pragma unroll 4
  for (int t = 0; t < Tt; ++t) {
    f16x8 af = {0,0,0,0,0,0,0,0}, bf = {0,0,0,0,0,0,0,0};
    if (realk) {
      af = *(const f16x8*)&kh[((size_t)t*Nn + i0 + l15)*HD + lk*8];
      bf = *(const f16x8*)&qh[((size_t)t*Nn + j0 + l15)*HD + lk*8];
    }
    f32x4 sc = {0.f,0.f,0.f,0.f};
    sc = __builtin_amdgcn_mfma_f32_16x16x32_f16(af, bf, sc, 0, 0, 0);
    float4 w1 = *(const float4*)&vw1_l[t][i0 + lk*4];
    float4 w2 = *(const float4*)&vw2_l[t][i0 + lk*4];
    const float* w1p = (const float*)&w1;
    const float* w2p = (const float*)&w2;
    #pragma unroll
    for (int r = 0; r < 4; ++r) {
      float s = fminf(fmaxf(sc[r] * scale, -60.f), 60.f);
      float ee = __expf(s);
      S[r] += ee;
      A1[r] = fmaf(ee, w1p[r], A1[r]);
      A2[r] = fmaf(ee, w2p[r], A2[r]);
    }
  }
  {
    const int j = j0 + l15;
    #pragma unroll
    for (int r = 0; r < 4; ++r) {
      const int i = i0 + lk*4 + r;
      float inv = 1.f / S[r];
      atomicAdd(&e[i*Nn + j], A1[r] * inv);
      atomicAdd(&e[j*Nn + i], A2[r] * inv);
    }
  }
}

// ---------------- kernel 4: decode GRU step + vv (ys read f16) ----------------
__global__ __launch_bounds__(384) void k_decode(
    const float* __restrict__ x, const float* __restrict__ W_hh,
    const float* __restrict__ b_hh, const float* __restrict__ W_val,
    const float* __restrict__ b_val, float* __restrict__ ws) {
  __shared__ float h_lds[4][Dd];
  __shared__ float g_lds[4][4*Dd];
  __shared__ float xt[4][Ss];
  const int tid = threadIdx.x;
  const int blk = blockIdx.x;
  const int row0 = blk * 4;
  const int b = row0 >> 6;
  const int n0 = row0 & 63;
  const _Float16* ysf = (const _Float16*)(ws + OFF_YS);
  const float* Wx = ws + OFF_WX;
  const float* bxp = ws + OFF_BX;
  if (tid < Dd) {
    for (int r = 0; r < 4; ++r)
      h_lds[r][tid] = (float)ysf[(size_t)((Tt-1)*BN + row0 + r)*Dd + tid];
  }
  if (tid >= 320 && tid < 336) {
    int q = tid - 320; int r = q >> 2, s = q & 3;
    xt[r][s] = x[((size_t)(b*(Tt+1) + Tt)*Nn + (n0 + r))*Ss + s];
  }
  const int c = tid;
  const float bhh = b_hh[c];
  const float wx0 = Wx[0*G3 + c], wx1 = Wx[1*G3 + c], wx2 = Wx[2*G3 + c], wx3 = Wx[3*G3 + c];
  const float bxv = bxp[c];
  __syncthreads();
  float acc[4] = {bhh, bhh, bhh, bhh};
  for (int k = 0; k < Dd; k += 4) {
    float w0 = W_hh[(k+0)*G3 + c];
    float w1 = W_hh[(k+1)*G3 + c];
    float w2 = W_hh[(k+2)*G3 + c];
    float w3 = W_hh[(k+3)*G3 + c];
    #pragma unroll
    for (int r = 0; r < 4; ++r) {
      float4 hv = *(const float4*)&h_lds[r][k];
      acc[r] = fmaf(hv.x, w0, acc[r]);
      acc[r] = fmaf(hv.y, w1, acc[r]);
      acc[r] = fmaf(hv.z, w2, acc[r]);
      acc[r] = fmaf(hv.w, w3, acc[r]);
    }
  }
  float gi[4];
  #pragma unroll
  for (int r = 0; r < 4; ++r) {
    float g = bxv;
    g = fmaf(xt[r][0], wx0, g);
    g = fmaf(xt[r][1], wx1, g);
    g = fmaf(xt[r][2], wx2, g);
    g = fmaf(xt[r][3], wx3, g);
    gi[r] = g;
  }
  if (c < 2*Dd) {
    #pragma unroll
    for (int r = 0; r < 4; ++r) g_lds[r][c] = acc[r] + gi[r];
  } else {
    #pragma unroll
    for (int r = 0; r < 4; ++r) { g_lds[r][c] = gi[r]; g_lds[r][c + Dd] = acc[r]; }
  }
  __syncthreads();
  if (tid < Dd) {
    const int d = tid;
    #pragma unroll
    for (int r = 0; r < 4; ++r) {
      float rg = fast_sigmoid(g_lds[r][d]);
      float zg = fast_sigmoid(g_lds[r][Dd + d]);
      float ng = fast_tanh(fmaf(rg, g_lds[r][3*Dd + d], g_lds[r][2*Dd + d]));
      float hn = fmaf(zg, h_lds[r][d] - ng, ng);
      h_lds[r][d] = hn;
    }
  }
  __syncthreads();
  if (tid < Dd) {
    const int c2 = tid;
    for (int r = 0; r < 4; ++r) {
      float a = b_val[c2];
      for (int k = 0; k < Dd; k += 4) {
        float4 hv = *(const float4*)&h_lds[r][k];
        a = fmaf(hv.x, W_val[(k+0)*Dd + c2], a);
        a = fmaf(hv.y, W_val[(k+1)*Dd + c2], a);
        a = fmaf(hv.z, W_val[(k+2)*Dd + c2], a);
        a = fmaf(hv.w, W_val[(k+3)*Dd + c2], a);
      }
      ws[OFF_VV + (size_t)(row0 + r)*Dd + c2] = a;
    }
  }
}

// ---------------- kernel 5: weight/p/dec/mu/sig — all via MFMA ----------------
__global__ __launch_bounds__(256) void k_final(
    const float* __restrict__ b_dec, const float* __restrict__ b_mu,
    const float* __restrict__ b_sig, const float* __restrict__ b_att,
    float* __restrict__ ws, float* __restrict__ out) {
  __shared__ __align__(16) _Float16 vvT[Dd][72];
  __shared__ __align__(16) _Float16 wl[16][72];
  __shared__ __align__(16) _Float16 A2[16][264];
  __shared__ __align__(16) _Float16 A3[16][136];
  const int tid = threadIdx.x;
  const int wave = tid >> 6, lane = tid & 63;
  const int l15 = lane & 15, lk = lane >> 4;
  const int blk = blockIdx.x;
  const int b = blk >> 2, iq = blk & 3, i0 = iq*16;
  const float* vv = ws + OFF_VV + (size_t)b*64*Dd;
  const float* e  = ws + OFF_E + (size_t)b*Nn*Nn;
  const float batt = b_att[0];

  for (int idx = tid; idx < 64*Dd/4; idx += 256) {
    int r = idx >> 5, k4 = (idx & 31)*4;
    float4 v = *(const float4*)&vv[r*Dd + k4];
    vvT[k4+0][r] = (_Float16)v.x;
    vvT[k4+1][r] = (_Float16)v.y;
    vvT[k4+2][r] = (_Float16)v.z;
    vvT[k4+3][r] = (_Float16)v.w;
    int rl = r - i0;
    if (rl >= 0 && rl < 16) {
      A2[rl][k4+0] = (_Float16)v.x;
      A2[rl][k4+1] = (_Float16)v.y;
      A2[rl][k4+2] = (_Float16)v.z;
      A2[rl][k4+3] = (_Float16)v.w;
    }
  }
  for (int idx = tid; idx < 16*64; idx += 256) {
    int il = idx >> 6, jj = idx & 63;
    int i = i0 + il;
    float v = (i == jj) ? 0.f : fast_tanh(e[i*Nn + jj] + batt + 0.5f);
    wl[il][jj] = (_Float16)v;
  }
  __syncthreads();

  {
    f16x8 a0 = *(const f16x8*)&wl[l15][lk*8];
    f16x8 a1 = *(const f16x8*)&wl[l15][32 + lk*8];
    #pragma unroll
    for (int q = 0; q < 2; ++q) {
      const int nt = wave*2 + q;
      f16x8 b0 = *(const f16x8*)&vvT[nt*16 + l15][lk*8];
      f16x8 b1 = *(const f16x8*)&vvT[nt*16 + l15][32 + lk*8];
      f32x4 acc = {0.f,0.f,0.f,0.f};
      acc = __builtin_amdgcn_mfma_f32_16x16x32_f16(a0, b0, acc, 0, 0, 0);
      acc = __builtin_amdgcn_mfma_f32_16x16x32_f16(a1, b1, acc, 0, 0, 0);
      #pragma unroll
      for (int r = 0; r < 4; ++r)
        A2[lk*4 + r][128 + nt*16 + l15] = (_Float16)(acc[r] * (1.f/64.f));
    }
  }
  __syncthreads();

  const f16x8* WDF = (const f16x8*)(ws + OFF_WDF);
  {
    f16x8 ad[8];
    #pragma unroll
    for (int ks = 0; ks < 8; ++ks)
      ad[ks] = *(const f16x8*)&A2[l15][ks*32 + lk*8];
    #pragma unroll
    for (int q = 0; q < 2; ++q) {
      const int nt = wave*2 + q;
      const float bias = b_dec[nt*16 + l15];
      f32x4 acc = {bias, bias, bias, bias};
      #pragma unroll
      for (int ks = 0; ks < 8; ++ks)
        acc = __builtin_amdgcn_mfma_f32_16x16x32_f16(
            ad[ks], WDF[(size_t)((nt*8 + ks)*64) + lane], acc, 0, 0, 0);
      #pragma unroll
      for (int r = 0; r < 4; ++r)
        A3[lk*4 + r][nt*16 + l15] = (_Float16)acc[r];
    }
  }
  __syncthreads();

  if (wave == 0) {
    const f16x8* WMF = (const f16x8*)(ws + OFF_WMF);
    f16x8 ah[4];
    #pragma unroll
    for (int ks = 0; ks < 4; ++ks)
      ah[ks] = *(const f16x8*)&A3[l15][ks*32 + lk*8];
    const float bias = (l15 < 4) ? b_mu[l15] : ((l15 < 8) ? b_sig[l15 - 4] : 0.f);
    f32x4 acc = {bias, bias, bias, bias};
    #pragma unroll
    for (int ks = 0; ks < 4; ++ks)
      acc = __builtin_amdgcn_mfma_f32_16x16x32_f16(
          ah[ks], WMF[(size_t)(ks*64) + lane], acc, 0, 0, 0);
    if (l15 < 8) {
      const int which = l15 >> 2, s = l15 & 3;
      #pragma unroll
      for (int r = 0; r < 4; ++r) {
        float v = acc[r];
        if (which) v = 1.f/(1.f + __expf(-v)) + 1e-6f;
        out[(size_t)which*(Bb*Nn*Ss) + (size_t)(b*64 + i0 + lk*4 + r)*Ss + s] = v;
      }
    }
  }
}

extern "C" void kernel_launch(void* const* d_in, const int* in_sizes, int n_in,
                              void* d_out, int out_size, void* d_ws, size_t ws_size,
                              hipStream_t stream) {
  const float* x     = (const float*)d_in[0];
  const float* W_se  = (const float*)d_in[1];
  const float* b_se  = (const float*)d_in[2];
  const float* W_init= (const float*)d_in[3];
  const float* b_init= (const float*)d_in[4];
  const float* W_ih  = (const float*)d_in[5];
  const float* W_hh  = (const float*)d_in[6];
  const float* b_ih  = (const float*)d_in[7];
  const float* b_hh  = (const float*)d_in[8];
  const float* W_kc  = (const float*)d_in[9];
  const float* W_qc  = (const float*)d_in[10];
  const float* W_vc  = (const float*)d_in[11];
  const float* W_att = (const float*)d_in[12];
  const float* b_att = (const float*)d_in[13];
  const float* W_val = (const float*)d_in[14];
  const float* b_val = (const float*)d_in[15];
  const float* W_dec = (const float*)d_in[16];
  const float* b_dec = (const float*)d_in[17];
  const float* W_mu  = (const float*)d_in[18];
  const float* b_mu  = (const float*)d_in[19];
  const float* W_sig = (const float*)d_in[20];
  const float* b_sig = (const float*)d_in[21];
  float* ws = (float*)d_ws;
  float* out = (float*)d_out;

  if (ws_size < (size_t)WS_FLOATS * sizeof(float)) return;

  k_precompute<<<52, 384, 0, stream>>>(W_se, b_se, W_ih, b_ih, W_hh, W_kc, W_qc,
                                       W_vc, W_att, W_dec, W_mu, W_sig, ws);
  k_gru<<<BN/4, 512, 0, stream>>>(x, W_init, b_init, b_hh, ws);
  k_kqv<<<Bb*Tt, 256, 0, stream>>>(ws);
  k_attn<<<Bb*Hh, 1024, 0, stream>>>(ws);
  k_decode<<<BN/4, 384, 0, stream>>>(x, W_hh, b_hh, W_val, b_val, ws);
  k_final<<<Bb*4, 256, 0, stream>>>(b_dec, b_mu, b_sig, b_att, ws, out);
}